// Round 3
// baseline (803.773 us; speedup 1.0000x reference)
//
#include <hip/hip_runtime.h>
#include <hip/hip_bf16.h>

// GCN 2-layer. With prescaled rows h'[v]=dinv[v]*h[v]:
//   agg[v] = dinv[v]*(h'[v] + sum_e h'[src_e]) + b
// CSR via bucket-binned counting sort (bucket-local rowptr/dinv).
// GEMMs via bf16 MFMA 16x16x32, epilogue scales by dinv and stores bf16.
// Aggregation: XCD-sliced, slice-major H[slice][node][16 dims] (32 B/node/slice,
//   3.2 MB/slice < 4 MB XCD L2; blockIdx%8 -> XCD). Round-2 lesson: traffic
//   fixed (FETCH 639->57 MB) but only 2 gathers in flight -> latency-bound.
//   Round-3: 4 nodes per wave x 16 edge-slots/iter = 8 independent predicated
//   gathers in flight; predicates from wave-uniform degrees (pipelineable).

#define D 128
#define BUKBITS 7          // 128 nodes per bucket
#define BUKSZ 128
#define MAXBUK 1024        // supports N <= 131072 (src < 2^25 packing)
#define SCHUNK 16384       // edges per scatter/hist block

#define NSLICE 8           // feature slices == XCDs
#define AGG_BLOCKS 1024    // 4 blocks/CU * 256 CUs co-resident at launch_bounds(256,4)
#define WAVES_PER_SLICE 512   // (AGG_BLOCKS/NSLICE) * 4 waves

typedef __attribute__((ext_vector_type(8))) short short8;
typedef __attribute__((ext_vector_type(4))) float f32x4;
typedef __attribute__((ext_vector_type(2))) float f32x2;

static __device__ __forceinline__ ushort f2b(float f) {
    __hip_bfloat16 h = __float2bfloat16(f);
    return *reinterpret_cast<ushort*>(&h);
}

// ---------------- CSR build ----------------

__global__ __launch_bounds__(256) void k_bukhist(const int* __restrict__ dst, int* __restrict__ bukcnt,
                                                 int E, int nbuk) {
    __shared__ int lh[MAXBUK];
    for (int i = threadIdx.x; i < nbuk; i += 256) lh[i] = 0;
    __syncthreads();
    int start = blockIdx.x * SCHUNK;
    int end = min(E, start + SCHUNK);
    for (int e = start + threadIdx.x; e < end; e += 256)
        atomicAdd(&lh[dst[e] >> BUKBITS], 1);
    __syncthreads();
    for (int i = threadIdx.x; i < nbuk; i += 256)
        if (lh[i]) atomicAdd(&bukcnt[i], lh[i]);
}

__global__ __launch_bounds__(256) void k_bukscan(const int* __restrict__ bukcnt, int* __restrict__ bukbase,
                                                 int* __restrict__ gcur, int nbuk, int E) {
    __shared__ int vals[MAXBUK];
    __shared__ int tsum[256];
    int t = threadIdx.x;
    for (int i = t; i < MAXBUK; i += 256) vals[i] = (i < nbuk) ? bukcnt[i] : 0;
    __syncthreads();
    int o = t * 4;
    int s = vals[o] + vals[o + 1] + vals[o + 2] + vals[o + 3];
    tsum[t] = s;
    __syncthreads();
    for (int off = 1; off < 256; off <<= 1) {
        int v = (t >= off) ? tsum[t - off] : 0;
        __syncthreads();
        tsum[t] += v;
        __syncthreads();
    }
    int run = tsum[t] - s;
    for (int i = 0; i < 4; i++) {
        int idx = o + i;
        if (idx < nbuk) { bukbase[idx] = run; gcur[idx] = run; }
        run += vals[idx];
    }
    if (t == 0) bukbase[nbuk] = E;
}

// edges -> bucket-grouped tmp: (dstLow << 25) | src
__global__ __launch_bounds__(256) void k_scatter(const int* __restrict__ src, const int* __restrict__ dst,
                                                 int* __restrict__ gcur, uint* __restrict__ tmp,
                                                 int E, int nbuk) {
    __shared__ int lh[MAXBUK];
    __shared__ int lbase[MAXBUK];
    for (int i = threadIdx.x; i < nbuk; i += 256) lh[i] = 0;
    __syncthreads();
    int start = blockIdx.x * SCHUNK;
    int end = min(E, start + SCHUNK);
    for (int e = start + threadIdx.x; e < end; e += 256)
        atomicAdd(&lh[dst[e] >> BUKBITS], 1);
    __syncthreads();
    for (int i = threadIdx.x; i < nbuk; i += 256) {
        int c = lh[i];
        lbase[i] = c ? atomicAdd(&gcur[i], c) : 0;
        lh[i] = 0;
    }
    __syncthreads();
    for (int e = start + threadIdx.x; e < end; e += 256) {
        int s = src[e];
        int d = dst[e];
        int bk = d >> BUKBITS;
        int r = atomicAdd(&lh[bk], 1);
        tmp[lbase[bk] + r] = ((uint)(d & (BUKSZ - 1)) << 25) | (uint)s;
    }
}

// bucket-local: per-node count, LDS scan -> rowptr+dinv, place eord
__global__ __launch_bounds__(256) void k_fillC(const uint* __restrict__ tmp, const int* __restrict__ bukbase,
                                               int* __restrict__ eord, int* __restrict__ rowptr,
                                               float* __restrict__ dinv, int n, int nbuk) {
    __shared__ int cnt[BUKSZ];
    __shared__ int sc[BUKSZ];
    __shared__ int lrp[BUKSZ];
    int b = blockIdx.x;
    int node0 = b << BUKBITS;
    int nn = min(BUKSZ, n - node0);
    int e0 = bukbase[b], e1 = bukbase[b + 1];
    int t = threadIdx.x;
    if (t < BUKSZ) cnt[t] = 0;
    __syncthreads();
    for (int e = e0 + t; e < e1; e += 256)
        atomicAdd(&cnt[tmp[e] >> 25], 1);
    __syncthreads();
    int c0 = (t < BUKSZ) ? cnt[t] : 0;
    if (t < BUKSZ) sc[t] = c0;
    __syncthreads();
    for (int off = 1; off < BUKSZ; off <<= 1) {
        int v = (t < BUKSZ && t >= off) ? sc[t - off] : 0;
        __syncthreads();
        if (t < BUKSZ) sc[t] += v;
        __syncthreads();
    }
    if (t < BUKSZ) lrp[t] = e0 + sc[t] - c0;
    if (t < nn) {
        rowptr[node0 + t] = e0 + sc[t] - c0;
        dinv[node0 + t] = 1.0f / sqrtf((float)(c0 + 1));  // +1 self-loop
    }
    if (b == nbuk - 1 && t == 0) rowptr[n] = e1;
    __syncthreads();
    if (t < BUKSZ) cnt[t] = 0;
    __syncthreads();
    for (int e = e0 + t; e < e1; e += 256) {
        uint u = tmp[e];
        int dL = (int)(u >> 25);
        int s = (int)(u & 0x1FFFFFFu);
        int r = atomicAdd(&cnt[dL], 1);
        eord[lrp[dL] + r] = s;
    }
}

// ---------------- W prep: transpose + bf16 (Wt[n][k]) ----------------
__global__ __launch_bounds__(256) void k_prepW(const float* __restrict__ W1, const float* __restrict__ W2,
                                               ushort* __restrict__ Wt1, ushort* __restrict__ Wt2) {
    int i = blockIdx.x * 256 + threadIdx.x;
    if (i < 16384) {
        int kk = i >> 7, nn = i & 127;
        Wt1[nn * 128 + kk] = f2b(W1[i]);
        Wt2[nn * 128 + kk] = f2b(W2[i]);
    }
}

// ---------------- MFMA GEMM: H[slice][row][m] = bf16(dinv[row] * (X[row] @ W)) ----------------
// A fp32 row-major (layer1) or bf16 SLICE-MAJOR (layer2).
// MFMA layouts (verified): A[m=lane&15][k=quad*8+j]; B[k][n=lane&15];
// D col=lane&15, row=quad*4+r.  Output dim = t*16+m -> slice=t, within=m.
template <bool ABF16>
__global__ __launch_bounds__(256) void k_gemm(const void* __restrict__ Xv, const ushort* __restrict__ Wt,
                                              const float* __restrict__ dinv, ushort* __restrict__ Hb,
                                              int nrows) {
    const int wave = threadIdx.x >> 6;
    const int lane = threadIdx.x & 63;
    const int quad = lane >> 4;
    const int m = lane & 15;
    const int row0 = blockIdx.x * 64 + wave * 16;
    const int rowc = min(row0 + m, nrows - 1);

    f32x4 acc[8];
    #pragma unroll
    for (int t = 0; t < 8; t++) acc[t] = (f32x4){0.f, 0.f, 0.f, 0.f};

    #pragma unroll
    for (int ks = 0; ks < 4; ks++) {
        const int k0 = ks * 32 + quad * 8;
        short8 a;
        if (ABF16) {
            // slice-major: slice = k0>>4, within-slice offset = k0&15 (8-aligned, fits in slice)
            const ushort* p = (const ushort*)Xv + (size_t)(k0 >> 4) * nrows * 16
                              + (size_t)rowc * 16 + (k0 & 15);
            a = *(const short8*)p;
        } else {
            const float* p = (const float*)Xv + (size_t)rowc * D + k0;
            float4 u0 = ((const float4*)p)[0];
            float4 u1 = ((const float4*)p)[1];
            a[0] = (short)f2b(u0.x); a[1] = (short)f2b(u0.y);
            a[2] = (short)f2b(u0.z); a[3] = (short)f2b(u0.w);
            a[4] = (short)f2b(u1.x); a[5] = (short)f2b(u1.y);
            a[6] = (short)f2b(u1.z); a[7] = (short)f2b(u1.w);
        }
        #pragma unroll
        for (int t = 0; t < 8; t++) {
            short8 b = *(const short8*)(Wt + ((t * 16 + m) * D + k0));
            acc[t] = __builtin_amdgcn_mfma_f32_16x16x32_bf16(a, b, acc[t], 0, 0, 0);
        }
    }
    #pragma unroll
    for (int r = 0; r < 4; r++) {
        int orow = row0 + quad * 4 + r;
        if (orow < nrows) {
            float dvv = dinv[orow];
            #pragma unroll
            for (int t = 0; t < 8; t++)
                Hb[(size_t)t * nrows * 16 + (size_t)orow * 16 + m] = f2b(acc[t][r] * dvv);
        }
    }
}

// ---------------- XCD-sliced CSR aggregation (slice-major H, 4 nodes/wave) ----------------
// Block b -> slice b%8 (-> XCD b%8). Wave: 4 consecutive nodes; per iteration
// 16 edge-slots per node -> 8 independent predicated gathers in flight.
// Degrees are wave-uniform -> predicates independent of load results.
// Butterfly-reduce over the 8 edge-groups per node; lanes 0..31 (group i)
// write node v0+i's 32 B chunk.
template <bool RELU, bool OBF16>
__global__ __launch_bounds__(256, 4) void k_agg_slice(const ushort* __restrict__ Hb,
                                                      const float* __restrict__ dinv,
                                                      const int* __restrict__ rowptr,
                                                      const int* __restrict__ eord,
                                                      const float* __restrict__ bias,
                                                      void* __restrict__ outp, int n) {
    const int slice = blockIdx.x & (NSLICE - 1);
    const int blk = blockIdx.x >> 3;                      // block index within slice
    const int wid = (blk << 2) + (threadIdx.x >> 6);      // wave index within slice [0,512)
    const int lane = threadIdx.x & 63;
    const int g = lane >> 3;                              // edge subgroup 0..7
    const int w = lane & 7;                               // dword within slice 0..7
    const int cofs = slice * 8 + w;                       // dword offset within 64-dword row
    const uint* __restrict__ Hu = (const uint*)Hb;
    const size_t sbase = (size_t)slice * n * 8;           // dword base of this slice
    const float2 bb = ((const float2*)bias)[cofs];

    for (int v0 = wid * 4; v0 < n; v0 += WAVES_PER_SLICE * 4) {
        // wave-uniform rowptr reads (scalarized by compiler)
        int rp0 = rowptr[v0];
        int rp1 = rowptr[min(v0 + 1, n)];
        int rp2 = rowptr[min(v0 + 2, n)];
        int rp3 = rowptr[min(v0 + 3, n)];
        int rp4 = rowptr[min(v0 + 4, n)];
        int d0 = rp1 - rp0, d1 = rp2 - rp1, d2 = rp3 - rp2, d3 = rp4 - rp3;
        int maxd = max(max(d0, d1), max(d2, d3));

        float ax0 = 0.f, ay0 = 0.f, ax1 = 0.f, ay1 = 0.f;
        float ax2 = 0.f, ay2 = 0.f, ax3 = 0.f, ay3 = 0.f;

        for (int k = 0; k < maxd; k += 16) {
            const int oA = k + g;
            const int oB = oA + 8;
            uint h;
#define GATH(RP, DD, AX, AY)                                                              \
            h = 0;                                                                        \
            if (oA < DD) {                                                                \
                int s_ = __builtin_nontemporal_load(eord + RP + oA);                      \
                h = Hu[sbase + (size_t)s_ * 8 + w];                                       \
            }                                                                             \
            AX += __uint_as_float(h << 16);                                               \
            AY += __uint_as_float(h & 0xffff0000u);                                       \
            h = 0;                                                                        \
            if (oB < DD) {                                                                \
                int s_ = __builtin_nontemporal_load(eord + RP + oB);                      \
                h = Hu[sbase + (size_t)s_ * 8 + w];                                       \
            }                                                                             \
            AX += __uint_as_float(h << 16);                                               \
            AY += __uint_as_float(h & 0xffff0000u);
            GATH(rp0, d0, ax0, ay0)
            GATH(rp1, d1, ax1, ay1)
            GATH(rp2, d2, ax2, ay2)
            GATH(rp3, d3, ax3, ay3)
#undef GATH
        }

        // butterfly over the 8 edge-groups (lanes with equal w)
        ax0 += __shfl_xor(ax0, 8);  ay0 += __shfl_xor(ay0, 8);
        ax1 += __shfl_xor(ax1, 8);  ay1 += __shfl_xor(ay1, 8);
        ax2 += __shfl_xor(ax2, 8);  ay2 += __shfl_xor(ay2, 8);
        ax3 += __shfl_xor(ax3, 8);  ay3 += __shfl_xor(ay3, 8);
        ax0 += __shfl_xor(ax0, 16); ay0 += __shfl_xor(ay0, 16);
        ax1 += __shfl_xor(ax1, 16); ay1 += __shfl_xor(ay1, 16);
        ax2 += __shfl_xor(ax2, 16); ay2 += __shfl_xor(ay2, 16);
        ax3 += __shfl_xor(ax3, 16); ay3 += __shfl_xor(ay3, 16);
        ax0 += __shfl_xor(ax0, 32); ay0 += __shfl_xor(ay0, 32);
        ax1 += __shfl_xor(ax1, 32); ay1 += __shfl_xor(ay1, 32);
        ax2 += __shfl_xor(ax2, 32); ay2 += __shfl_xor(ay2, 32);
        ax3 += __shfl_xor(ax3, 32); ay3 += __shfl_xor(ay3, 32);

        // group i (lanes 8i..8i+7, i<4) writes node v0+i
        const int i = g;
        if (i < 4) {
            int v = v0 + i;
            if (v < n) {
                float axv = (i == 0) ? ax0 : (i == 1) ? ax1 : (i == 2) ? ax2 : ax3;
                float ayv = (i == 0) ? ay0 : (i == 1) ? ay1 : (i == 2) ? ay2 : ay3;
                uint hs = Hu[sbase + (size_t)v * 8 + w];   // self-loop term (resident slice)
                float dv = dinv[v];
                float rx = dv * (axv + __uint_as_float(hs << 16)) + bb.x;
                float ry = dv * (ayv + __uint_as_float(hs & 0xffff0000u)) + bb.y;
                if (RELU) { rx = fmaxf(rx, 0.f); ry = fmaxf(ry, 0.f); }
                if (OBF16) {
                    uint wd = ((uint)f2b(ry) << 16) | (uint)f2b(rx);
                    __builtin_nontemporal_store(wd, (uint*)outp + sbase + (size_t)v * 8 + w);
                } else {
                    f32x2 r2 = {rx, ry};
                    __builtin_nontemporal_store(r2, (f32x2*)outp + (size_t)v * 64 + cofs);
                }
            }
        }
    }
}

// ---------------- launcher ----------------

static inline size_t alignup(size_t x) { return (x + 511) & ~(size_t)511; }

extern "C" void kernel_launch(void* const* d_in, const int* in_sizes, int n_in,
                              void* d_out, int out_size, void* d_ws, size_t ws_size,
                              hipStream_t stream) {
    const float* x  = (const float*)d_in[0];
    const int* eidx = (const int*)d_in[1];   // [2,E]: src row, dst row (int32)
    const float* W1 = (const float*)d_in[2];
    const float* b1 = (const float*)d_in[3];
    const float* W2 = (const float*)d_in[4];
    const float* b2 = (const float*)d_in[5];
    float* out = (float*)d_out;

    const int N = in_sizes[0] / D;
    const int E = in_sizes[1] / 2;
    const int* src = eidx;
    const int* dst = eidx + E;
    const int nbuk = (N + BUKSZ - 1) >> BUKBITS;   // 782

    // workspace
    char* ws = (char*)d_ws;
    size_t off = 0;
    int* bukcnt = (int*)(ws + off);   off = alignup(off + (size_t)MAXBUK * 4);
    int* bukbase = (int*)(ws + off);  off = alignup(off + (size_t)(MAXBUK + 1) * 4);
    int* gcur   = (int*)(ws + off);   off = alignup(off + (size_t)MAXBUK * 4);
    int* rowptr = (int*)(ws + off);   off = alignup(off + (size_t)(N + 1) * 4);
    float* dinv = (float*)(ws + off); off = alignup(off + (size_t)N * 4);
    int* eord   = (int*)(ws + off);   off = alignup(off + (size_t)E * 4);
    ushort* hbuf = (ushort*)(ws + off); off = alignup(off + (size_t)N * D * 2);
    ushort* act  = (ushort*)(ws + off); off = alignup(off + (size_t)N * D * 2);
    ushort* Wt1 = (ushort*)(ws + off); off = alignup(off + 16384 * 2);
    ushort* Wt2 = (ushort*)(ws + off); off = alignup(off + 16384 * 2);
    uint* tmp = (uint*)hbuf;  // E uints (6.4 MB) alias hbuf; dead before gemm1 writes
    (void)ws_size;

    const int nT = 256;
    const int gChunk = (E + SCHUNK - 1) / SCHUNK;   // 98

    hipMemsetAsync(bukcnt, 0, (size_t)MAXBUK * 4, stream);
    k_prepW<<<64, nT, 0, stream>>>(W1, W2, Wt1, Wt2);
    k_bukhist<<<gChunk, nT, 0, stream>>>(dst, bukcnt, E, nbuk);
    k_bukscan<<<1, nT, 0, stream>>>(bukcnt, bukbase, gcur, nbuk, E);
    k_scatter<<<gChunk, nT, 0, stream>>>(src, dst, gcur, tmp, E, nbuk);
    k_fillC<<<nbuk, nT, 0, stream>>>(tmp, bukbase, eord, rowptr, dinv, N, nbuk);

    const int gGemm = (N + 63) / 64;

    // layer 1: hbuf = bf16(dinv*(x @ W1)) slice-major; act(bf16 slice-major) = relu(agg + b1)
    k_gemm<false><<<gGemm, nT, 0, stream>>>((const void*)x, Wt1, dinv, hbuf, N);
    k_agg_slice<true, true><<<AGG_BLOCKS, nT, 0, stream>>>(hbuf, dinv, rowptr, eord, b1, (void*)act, N);

    // layer 2: hbuf = bf16(dinv*(act @ W2)) slice-major; out(fp32 row-major) = agg + b2
    k_gemm<true><<<gGemm, nT, 0, stream>>>((const void*)act, Wt2, dinv, hbuf, N);
    k_agg_slice<false, false><<<AGG_BLOCKS, nT, 0, stream>>>(hbuf, dinv, rowptr, eord, b2, (void*)out, N);
}

// Round 4
// 567.778 us; speedup vs baseline: 1.4156x; 1.4156x over previous
//
#include <hip/hip_runtime.h>
#include <hip/hip_bf16.h>

// GCN 2-layer. With prescaled rows h'[v]=dinv[v]*h[v]:
//   agg[v] = dinv[v]*(h'[v] + sum_e h'[src_e]) + b
// CSR via bucket-binned counting sort (bucket-local rowptr/dinv).
// GEMMs via bf16 MFMA 16x16x32, epilogue scales by dinv and stores bf16.
// Aggregation: XCD-sliced, slice-major H[slice][node][16 dims] (32 B/node/slice,
//   3.2 MB/slice < 4 MB XCD L2; blockIdx%8 -> XCD).
// Round-2: traffic fixed (FETCH 639->57 MB) but 2 gathers in flight.
// Round-3: predicated slots -> exec-mask branches blocked load batching; occupancy halved.
// Round-4: BRANCH-FREE straight-line gathers (clamped offsets + cndmask masking)
//   -> 8 eord loads + 8 gathers batched per iteration; 2048 blocks, lb(256,8).

#define D 128
#define BUKBITS 7          // 128 nodes per bucket
#define BUKSZ 128
#define MAXBUK 1024        // supports N <= 131072 (src < 2^25 packing)
#define SCHUNK 16384       // edges per scatter/hist block

#define NSLICE 8           // feature slices == XCDs
#define AGG_BLOCKS 2048    // 8 blocks/CU * 256 CUs co-resident at launch_bounds(256,8)
#define WAVES_PER_SLICE 1024  // (AGG_BLOCKS/NSLICE) * 4 waves

typedef __attribute__((ext_vector_type(8))) short short8;
typedef __attribute__((ext_vector_type(4))) float f32x4;
typedef __attribute__((ext_vector_type(2))) float f32x2;

static __device__ __forceinline__ ushort f2b(float f) {
    __hip_bfloat16 h = __float2bfloat16(f);
    return *reinterpret_cast<ushort*>(&h);
}

// ---------------- CSR build ----------------

__global__ __launch_bounds__(256) void k_bukhist(const int* __restrict__ dst, int* __restrict__ bukcnt,
                                                 int E, int nbuk) {
    __shared__ int lh[MAXBUK];
    for (int i = threadIdx.x; i < nbuk; i += 256) lh[i] = 0;
    __syncthreads();
    int start = blockIdx.x * SCHUNK;
    int end = min(E, start + SCHUNK);
    for (int e = start + threadIdx.x; e < end; e += 256)
        atomicAdd(&lh[dst[e] >> BUKBITS], 1);
    __syncthreads();
    for (int i = threadIdx.x; i < nbuk; i += 256)
        if (lh[i]) atomicAdd(&bukcnt[i], lh[i]);
}

__global__ __launch_bounds__(256) void k_bukscan(const int* __restrict__ bukcnt, int* __restrict__ bukbase,
                                                 int* __restrict__ gcur, int nbuk, int E) {
    __shared__ int vals[MAXBUK];
    __shared__ int tsum[256];
    int t = threadIdx.x;
    for (int i = t; i < MAXBUK; i += 256) vals[i] = (i < nbuk) ? bukcnt[i] : 0;
    __syncthreads();
    int o = t * 4;
    int s = vals[o] + vals[o + 1] + vals[o + 2] + vals[o + 3];
    tsum[t] = s;
    __syncthreads();
    for (int off = 1; off < 256; off <<= 1) {
        int v = (t >= off) ? tsum[t - off] : 0;
        __syncthreads();
        tsum[t] += v;
        __syncthreads();
    }
    int run = tsum[t] - s;
    for (int i = 0; i < 4; i++) {
        int idx = o + i;
        if (idx < nbuk) { bukbase[idx] = run; gcur[idx] = run; }
        run += vals[idx];
    }
    if (t == 0) bukbase[nbuk] = E;
}

// edges -> bucket-grouped tmp: (dstLow << 25) | src
__global__ __launch_bounds__(256) void k_scatter(const int* __restrict__ src, const int* __restrict__ dst,
                                                 int* __restrict__ gcur, uint* __restrict__ tmp,
                                                 int E, int nbuk) {
    __shared__ int lh[MAXBUK];
    __shared__ int lbase[MAXBUK];
    for (int i = threadIdx.x; i < nbuk; i += 256) lh[i] = 0;
    __syncthreads();
    int start = blockIdx.x * SCHUNK;
    int end = min(E, start + SCHUNK);
    for (int e = start + threadIdx.x; e < end; e += 256)
        atomicAdd(&lh[dst[e] >> BUKBITS], 1);
    __syncthreads();
    for (int i = threadIdx.x; i < nbuk; i += 256) {
        int c = lh[i];
        lbase[i] = c ? atomicAdd(&gcur[i], c) : 0;
        lh[i] = 0;
    }
    __syncthreads();
    for (int e = start + threadIdx.x; e < end; e += 256) {
        int s = src[e];
        int d = dst[e];
        int bk = d >> BUKBITS;
        int r = atomicAdd(&lh[bk], 1);
        tmp[lbase[bk] + r] = ((uint)(d & (BUKSZ - 1)) << 25) | (uint)s;
    }
}

// bucket-local: per-node count, LDS scan -> rowptr+dinv, place eord
__global__ __launch_bounds__(256) void k_fillC(const uint* __restrict__ tmp, const int* __restrict__ bukbase,
                                               int* __restrict__ eord, int* __restrict__ rowptr,
                                               float* __restrict__ dinv, int n, int nbuk) {
    __shared__ int cnt[BUKSZ];
    __shared__ int sc[BUKSZ];
    __shared__ int lrp[BUKSZ];
    int b = blockIdx.x;
    int node0 = b << BUKBITS;
    int nn = min(BUKSZ, n - node0);
    int e0 = bukbase[b], e1 = bukbase[b + 1];
    int t = threadIdx.x;
    if (t < BUKSZ) cnt[t] = 0;
    __syncthreads();
    for (int e = e0 + t; e < e1; e += 256)
        atomicAdd(&cnt[tmp[e] >> 25], 1);
    __syncthreads();
    int c0 = (t < BUKSZ) ? cnt[t] : 0;
    if (t < BUKSZ) sc[t] = c0;
    __syncthreads();
    for (int off = 1; off < BUKSZ; off <<= 1) {
        int v = (t < BUKSZ && t >= off) ? sc[t - off] : 0;
        __syncthreads();
        if (t < BUKSZ) sc[t] += v;
        __syncthreads();
    }
    if (t < BUKSZ) lrp[t] = e0 + sc[t] - c0;
    if (t < nn) {
        rowptr[node0 + t] = e0 + sc[t] - c0;
        dinv[node0 + t] = 1.0f / sqrtf((float)(c0 + 1));  // +1 self-loop
    }
    if (b == nbuk - 1 && t == 0) rowptr[n] = e1;
    __syncthreads();
    if (t < BUKSZ) cnt[t] = 0;
    __syncthreads();
    for (int e = e0 + t; e < e1; e += 256) {
        uint u = tmp[e];
        int dL = (int)(u >> 25);
        int s = (int)(u & 0x1FFFFFFu);
        int r = atomicAdd(&cnt[dL], 1);
        eord[lrp[dL] + r] = s;
    }
}

// ---------------- W prep: transpose + bf16 (Wt[n][k]) ----------------
__global__ __launch_bounds__(256) void k_prepW(const float* __restrict__ W1, const float* __restrict__ W2,
                                               ushort* __restrict__ Wt1, ushort* __restrict__ Wt2) {
    int i = blockIdx.x * 256 + threadIdx.x;
    if (i < 16384) {
        int kk = i >> 7, nn = i & 127;
        Wt1[nn * 128 + kk] = f2b(W1[i]);
        Wt2[nn * 128 + kk] = f2b(W2[i]);
    }
}

// ---------------- MFMA GEMM: H[slice][row][m] = bf16(dinv[row] * (X[row] @ W)) ----------------
// A fp32 row-major (layer1) or bf16 SLICE-MAJOR (layer2).
// MFMA layouts (verified): A[m=lane&15][k=quad*8+j]; B[k][n=lane&15];
// D col=lane&15, row=quad*4+r.  Output dim = t*16+m -> slice=t, within=m.
template <bool ABF16>
__global__ __launch_bounds__(256) void k_gemm(const void* __restrict__ Xv, const ushort* __restrict__ Wt,
                                              const float* __restrict__ dinv, ushort* __restrict__ Hb,
                                              int nrows) {
    const int wave = threadIdx.x >> 6;
    const int lane = threadIdx.x & 63;
    const int quad = lane >> 4;
    const int m = lane & 15;
    const int row0 = blockIdx.x * 64 + wave * 16;
    const int rowc = min(row0 + m, nrows - 1);

    f32x4 acc[8];
    #pragma unroll
    for (int t = 0; t < 8; t++) acc[t] = (f32x4){0.f, 0.f, 0.f, 0.f};

    #pragma unroll
    for (int ks = 0; ks < 4; ks++) {
        const int k0 = ks * 32 + quad * 8;
        short8 a;
        if (ABF16) {
            // slice-major: slice = k0>>4, within-slice offset = k0&15 (8-aligned, fits in slice)
            const ushort* p = (const ushort*)Xv + (size_t)(k0 >> 4) * nrows * 16
                              + (size_t)rowc * 16 + (k0 & 15);
            a = *(const short8*)p;
        } else {
            const float* p = (const float*)Xv + (size_t)rowc * D + k0;
            float4 u0 = ((const float4*)p)[0];
            float4 u1 = ((const float4*)p)[1];
            a[0] = (short)f2b(u0.x); a[1] = (short)f2b(u0.y);
            a[2] = (short)f2b(u0.z); a[3] = (short)f2b(u0.w);
            a[4] = (short)f2b(u1.x); a[5] = (short)f2b(u1.y);
            a[6] = (short)f2b(u1.z); a[7] = (short)f2b(u1.w);
        }
        #pragma unroll
        for (int t = 0; t < 8; t++) {
            short8 b = *(const short8*)(Wt + ((t * 16 + m) * D + k0));
            acc[t] = __builtin_amdgcn_mfma_f32_16x16x32_bf16(a, b, acc[t], 0, 0, 0);
        }
    }
    #pragma unroll
    for (int r = 0; r < 4; r++) {
        int orow = row0 + quad * 4 + r;
        if (orow < nrows) {
            float dvv = dinv[orow];
            #pragma unroll
            for (int t = 0; t < 8; t++)
                Hb[(size_t)t * nrows * 16 + (size_t)orow * 16 + m] = f2b(acc[t][r] * dvv);
        }
    }
}

// ---------------- XCD-sliced CSR aggregation (slice-major H, 4 nodes/wave) ----------------
// Block b -> slice b%8 (-> XCD b%8). Wave: 4 consecutive nodes; per iteration
// 16 edge-slots/node -> 8 eord loads + 8 gathers, ALL straight-line (clamped
// always-valid addresses; results masked by v_cndmask). No exec-mask branches
// -> compiler batches the loads back-to-back -> 8+ requests in flight/wave.
template <bool RELU, bool OBF16>
__global__ __launch_bounds__(256, 8) void k_agg_slice(const ushort* __restrict__ Hb,
                                                      const float* __restrict__ dinv,
                                                      const int* __restrict__ rowptr,
                                                      const int* __restrict__ eord,
                                                      const float* __restrict__ bias,
                                                      void* __restrict__ outp, int n) {
    const int slice = blockIdx.x & (NSLICE - 1);
    const int blk = blockIdx.x >> 3;                      // block index within slice
    const int wid = (blk << 2) + (threadIdx.x >> 6);      // wave index within slice [0,1024)
    const int lane = threadIdx.x & 63;
    const int g = lane >> 3;                              // edge subgroup 0..7
    const int w = lane & 7;                               // dword within slice 0..7
    const int cofs = slice * 8 + w;                       // dword offset within 64-dword row
    const uint* __restrict__ Hu = (const uint*)Hb;
    const size_t sbase = (size_t)slice * n * 8;           // dword base of this slice
    const uint nclamp = (uint)(n - 1);
    const float2 bb = ((const float2*)bias)[cofs];

    for (int v0 = wid * 4; v0 < n; v0 += WAVES_PER_SLICE * 4) {
        // wave-uniform rowptr reads (scalarized by compiler)
        int rp0 = rowptr[v0];
        int rp1 = rowptr[min(v0 + 1, n)];
        int rp2 = rowptr[min(v0 + 2, n)];
        int rp3 = rowptr[min(v0 + 3, n)];
        int rp4 = rowptr[min(v0 + 4, n)];
        int d0 = rp1 - rp0, d1 = rp2 - rp1, d2 = rp3 - rp2, d3 = rp4 - rp3;
        int maxd = max(max(d0, d1), max(d2, d3));

        float ax0 = 0.f, ay0 = 0.f, ax1 = 0.f, ay1 = 0.f;
        float ax2 = 0.f, ay2 = 0.f, ax3 = 0.f, ay3 = 0.f;

        for (int k = 0; k < maxd; k += 16) {
            const int oA = k + g;
            const int oB = oA + 8;
            // clamped, always-valid offsets (branch-free)
            int iA0 = rp0 + ((oA < d0) ? oA : 0);
            int iB0 = rp0 + ((oB < d0) ? oB : 0);
            int iA1 = rp1 + ((oA < d1) ? oA : 0);
            int iB1 = rp1 + ((oB < d1) ? oB : 0);
            int iA2 = rp2 + ((oA < d2) ? oA : 0);
            int iB2 = rp2 + ((oB < d2) ? oB : 0);
            int iA3 = rp3 + ((oA < d3) ? oA : 0);
            int iB3 = rp3 + ((oB < d3) ? oB : 0);
            // 8 independent index loads (batched)
            int sA0 = __builtin_nontemporal_load(eord + iA0);
            int sB0 = __builtin_nontemporal_load(eord + iB0);
            int sA1 = __builtin_nontemporal_load(eord + iA1);
            int sB1 = __builtin_nontemporal_load(eord + iB1);
            int sA2 = __builtin_nontemporal_load(eord + iA2);
            int sB2 = __builtin_nontemporal_load(eord + iB2);
            int sA3 = __builtin_nontemporal_load(eord + iA3);
            int sB3 = __builtin_nontemporal_load(eord + iB3);
            // 8 independent gathers (batched); index clamped into [0,n)
            uint hA0 = Hu[sbase + (size_t)min((uint)sA0, nclamp) * 8 + w];
            uint hB0 = Hu[sbase + (size_t)min((uint)sB0, nclamp) * 8 + w];
            uint hA1 = Hu[sbase + (size_t)min((uint)sA1, nclamp) * 8 + w];
            uint hB1 = Hu[sbase + (size_t)min((uint)sB1, nclamp) * 8 + w];
            uint hA2 = Hu[sbase + (size_t)min((uint)sA2, nclamp) * 8 + w];
            uint hB2 = Hu[sbase + (size_t)min((uint)sB2, nclamp) * 8 + w];
            uint hA3 = Hu[sbase + (size_t)min((uint)sA3, nclamp) * 8 + w];
            uint hB3 = Hu[sbase + (size_t)min((uint)sB3, nclamp) * 8 + w];
            // mask dead slots (cndmask, no branches)
            hA0 = (oA < d0) ? hA0 : 0u;  hB0 = (oB < d0) ? hB0 : 0u;
            hA1 = (oA < d1) ? hA1 : 0u;  hB1 = (oB < d1) ? hB1 : 0u;
            hA2 = (oA < d2) ? hA2 : 0u;  hB2 = (oB < d2) ? hB2 : 0u;
            hA3 = (oA < d3) ? hA3 : 0u;  hB3 = (oB < d3) ? hB3 : 0u;
            ax0 += __uint_as_float(hA0 << 16) + __uint_as_float(hB0 << 16);
            ay0 += __uint_as_float(hA0 & 0xffff0000u) + __uint_as_float(hB0 & 0xffff0000u);
            ax1 += __uint_as_float(hA1 << 16) + __uint_as_float(hB1 << 16);
            ay1 += __uint_as_float(hA1 & 0xffff0000u) + __uint_as_float(hB1 & 0xffff0000u);
            ax2 += __uint_as_float(hA2 << 16) + __uint_as_float(hB2 << 16);
            ay2 += __uint_as_float(hA2 & 0xffff0000u) + __uint_as_float(hB2 & 0xffff0000u);
            ax3 += __uint_as_float(hA3 << 16) + __uint_as_float(hB3 << 16);
            ay3 += __uint_as_float(hA3 & 0xffff0000u) + __uint_as_float(hB3 & 0xffff0000u);
        }

        // butterfly over the 8 edge-groups (lanes with equal w)
        ax0 += __shfl_xor(ax0, 8);  ay0 += __shfl_xor(ay0, 8);
        ax1 += __shfl_xor(ax1, 8);  ay1 += __shfl_xor(ay1, 8);
        ax2 += __shfl_xor(ax2, 8);  ay2 += __shfl_xor(ay2, 8);
        ax3 += __shfl_xor(ax3, 8);  ay3 += __shfl_xor(ay3, 8);
        ax0 += __shfl_xor(ax0, 16); ay0 += __shfl_xor(ay0, 16);
        ax1 += __shfl_xor(ax1, 16); ay1 += __shfl_xor(ay1, 16);
        ax2 += __shfl_xor(ax2, 16); ay2 += __shfl_xor(ay2, 16);
        ax3 += __shfl_xor(ax3, 16); ay3 += __shfl_xor(ay3, 16);
        ax0 += __shfl_xor(ax0, 32); ay0 += __shfl_xor(ay0, 32);
        ax1 += __shfl_xor(ax1, 32); ay1 += __shfl_xor(ay1, 32);
        ax2 += __shfl_xor(ax2, 32); ay2 += __shfl_xor(ay2, 32);
        ax3 += __shfl_xor(ax3, 32); ay3 += __shfl_xor(ay3, 32);

        // group i (lanes 8i..8i+7, i<4) writes node v0+i
        const int i = g;
        if (i < 4) {
            int v = v0 + i;
            if (v < n) {
                float axv = (i == 0) ? ax0 : (i == 1) ? ax1 : (i == 2) ? ax2 : ax3;
                float ayv = (i == 0) ? ay0 : (i == 1) ? ay1 : (i == 2) ? ay2 : ay3;
                uint hs = Hu[sbase + (size_t)v * 8 + w];   // self-loop term (resident slice)
                float dv = dinv[v];
                float rx = dv * (axv + __uint_as_float(hs << 16)) + bb.x;
                float ry = dv * (ayv + __uint_as_float(hs & 0xffff0000u)) + bb.y;
                if (RELU) { rx = fmaxf(rx, 0.f); ry = fmaxf(ry, 0.f); }
                if (OBF16) {
                    uint wd = ((uint)f2b(ry) << 16) | (uint)f2b(rx);
                    __builtin_nontemporal_store(wd, (uint*)outp + sbase + (size_t)v * 8 + w);
                } else {
                    f32x2 r2 = {rx, ry};
                    __builtin_nontemporal_store(r2, (f32x2*)outp + (size_t)v * 64 + cofs);
                }
            }
        }
    }
}

// ---------------- launcher ----------------

static inline size_t alignup(size_t x) { return (x + 511) & ~(size_t)511; }

extern "C" void kernel_launch(void* const* d_in, const int* in_sizes, int n_in,
                              void* d_out, int out_size, void* d_ws, size_t ws_size,
                              hipStream_t stream) {
    const float* x  = (const float*)d_in[0];
    const int* eidx = (const int*)d_in[1];   // [2,E]: src row, dst row (int32)
    const float* W1 = (const float*)d_in[2];
    const float* b1 = (const float*)d_in[3];
    const float* W2 = (const float*)d_in[4];
    const float* b2 = (const float*)d_in[5];
    float* out = (float*)d_out;

    const int N = in_sizes[0] / D;
    const int E = in_sizes[1] / 2;
    const int* src = eidx;
    const int* dst = eidx + E;
    const int nbuk = (N + BUKSZ - 1) >> BUKBITS;   // 782

    // workspace
    char* ws = (char*)d_ws;
    size_t off = 0;
    int* bukcnt = (int*)(ws + off);   off = alignup(off + (size_t)MAXBUK * 4);
    int* bukbase = (int*)(ws + off);  off = alignup(off + (size_t)(MAXBUK + 1) * 4);
    int* gcur   = (int*)(ws + off);   off = alignup(off + (size_t)MAXBUK * 4);
    int* rowptr = (int*)(ws + off);   off = alignup(off + (size_t)(N + 1) * 4);
    float* dinv = (float*)(ws + off); off = alignup(off + (size_t)N * 4);
    int* eord   = (int*)(ws + off);   off = alignup(off + (size_t)(E + 16) * 4);
    ushort* hbuf = (ushort*)(ws + off); off = alignup(off + (size_t)N * D * 2);
    ushort* act  = (ushort*)(ws + off); off = alignup(off + (size_t)N * D * 2);
    ushort* Wt1 = (ushort*)(ws + off); off = alignup(off + 16384 * 2);
    ushort* Wt2 = (ushort*)(ws + off); off = alignup(off + 16384 * 2);
    uint* tmp = (uint*)hbuf;  // E uints (6.4 MB) alias hbuf; dead before gemm1 writes
    (void)ws_size;

    const int nT = 256;
    const int gChunk = (E + SCHUNK - 1) / SCHUNK;   // 98

    hipMemsetAsync(bukcnt, 0, (size_t)MAXBUK * 4, stream);
    k_prepW<<<64, nT, 0, stream>>>(W1, W2, Wt1, Wt2);
    k_bukhist<<<gChunk, nT, 0, stream>>>(dst, bukcnt, E, nbuk);
    k_bukscan<<<1, nT, 0, stream>>>(bukcnt, bukbase, gcur, nbuk, E);
    k_scatter<<<gChunk, nT, 0, stream>>>(src, dst, gcur, tmp, E, nbuk);
    k_fillC<<<nbuk, nT, 0, stream>>>(tmp, bukbase, eord, rowptr, dinv, N, nbuk);

    const int gGemm = (N + 63) / 64;

    // layer 1: hbuf = bf16(dinv*(x @ W1)) slice-major; act(bf16 slice-major) = relu(agg + b1)
    k_gemm<false><<<gGemm, nT, 0, stream>>>((const void*)x, Wt1, dinv, hbuf, N);
    k_agg_slice<true, true><<<AGG_BLOCKS, nT, 0, stream>>>(hbuf, dinv, rowptr, eord, b1, (void*)act, N);

    // layer 2: hbuf = bf16(dinv*(act @ W2)) slice-major; out(fp32 row-major) = agg + b2
    k_gemm<true><<<gGemm, nT, 0, stream>>>((const void*)act, Wt2, dinv, hbuf, N);
    k_agg_slice<false, false><<<AGG_BLOCKS, nT, 0, stream>>>(hbuf, dinv, rowptr, eord, b2, (void*)out, N);
}

// Round 5
// 461.780 us; speedup vs baseline: 1.7406x; 1.2295x over previous
//
#include <hip/hip_runtime.h>
#include <hip/hip_bf16.h>

// GCN 2-layer. With prescaled rows h'[v]=dinv[v]*h[v]:
//   agg[v] = dinv[v]*(h'[v] + sum_e h'[src_e]) + b
// CSR via bucket-binned counting sort (bucket-local rowptr/dinv).
// GEMMs via bf16 MFMA 16x16x32, epilogue scales by dinv and stores bf16.
// Aggregation: XCD-sliced, slice-major H[slice][node][16 dims] (32 B/node/slice,
//   3.2 MB/slice < 4 MB XCD L2; blockIdx%8 -> XCD).
// R2: traffic fixed (FETCH 639->57 MB), latency-bound. R3: exec-mask branches
// blocked batching. R4: branch-free -> 170us, but 2x VALU fat + no pipelining
// (VGPR=24) + 50% dead slots.
// R5: zero-row trick (n+1 rows/slice, row n = 0; eord pad [E,E+16)=n) removes
//   h-mask cmp/cndmask + min-clamp; 32-bit slice-local gather addressing;
//   manual 2-stage pipeline (next iter's 8 idx loads issued before consuming
//   current gathers) -> 16 loads in flight/wave, eord latency hidden.

#define D 128
#define BUKBITS 7          // 128 nodes per bucket
#define BUKSZ 128
#define MAXBUK 1024        // supports N <= 131072 (src < 2^25 packing)
#define SCHUNK 16384       // edges per scatter/hist block

#define NSLICE 8           // feature slices == XCDs
#define AGG_BLOCKS 2048    // 8 blocks/CU * 256 CUs co-resident at launch_bounds(256,8)
#define WAVES_PER_SLICE 1024  // (AGG_BLOCKS/NSLICE) * 4 waves

typedef __attribute__((ext_vector_type(8))) short short8;
typedef __attribute__((ext_vector_type(4))) float f32x4;
typedef __attribute__((ext_vector_type(2))) float f32x2;

static __device__ __forceinline__ ushort f2b(float f) {
    __hip_bfloat16 h = __float2bfloat16(f);
    return *reinterpret_cast<ushort*>(&h);
}

// ---------------- CSR build ----------------

__global__ __launch_bounds__(256) void k_bukhist(const int* __restrict__ dst, int* __restrict__ bukcnt,
                                                 int E, int nbuk) {
    __shared__ int lh[MAXBUK];
    for (int i = threadIdx.x; i < nbuk; i += 256) lh[i] = 0;
    __syncthreads();
    int start = blockIdx.x * SCHUNK;
    int end = min(E, start + SCHUNK);
    for (int e = start + threadIdx.x; e < end; e += 256)
        atomicAdd(&lh[dst[e] >> BUKBITS], 1);
    __syncthreads();
    for (int i = threadIdx.x; i < nbuk; i += 256)
        if (lh[i]) atomicAdd(&bukcnt[i], lh[i]);
}

__global__ __launch_bounds__(256) void k_bukscan(const int* __restrict__ bukcnt, int* __restrict__ bukbase,
                                                 int* __restrict__ gcur, int nbuk, int E) {
    __shared__ int vals[MAXBUK];
    __shared__ int tsum[256];
    int t = threadIdx.x;
    for (int i = t; i < MAXBUK; i += 256) vals[i] = (i < nbuk) ? bukcnt[i] : 0;
    __syncthreads();
    int o = t * 4;
    int s = vals[o] + vals[o + 1] + vals[o + 2] + vals[o + 3];
    tsum[t] = s;
    __syncthreads();
    for (int off = 1; off < 256; off <<= 1) {
        int v = (t >= off) ? tsum[t - off] : 0;
        __syncthreads();
        tsum[t] += v;
        __syncthreads();
    }
    int run = tsum[t] - s;
    for (int i = 0; i < 4; i++) {
        int idx = o + i;
        if (idx < nbuk) { bukbase[idx] = run; gcur[idx] = run; }
        run += vals[idx];
    }
    if (t == 0) bukbase[nbuk] = E;
}

// edges -> bucket-grouped tmp: (dstLow << 25) | src
__global__ __launch_bounds__(256) void k_scatter(const int* __restrict__ src, const int* __restrict__ dst,
                                                 int* __restrict__ gcur, uint* __restrict__ tmp,
                                                 int E, int nbuk) {
    __shared__ int lh[MAXBUK];
    __shared__ int lbase[MAXBUK];
    for (int i = threadIdx.x; i < nbuk; i += 256) lh[i] = 0;
    __syncthreads();
    int start = blockIdx.x * SCHUNK;
    int end = min(E, start + SCHUNK);
    for (int e = start + threadIdx.x; e < end; e += 256)
        atomicAdd(&lh[dst[e] >> BUKBITS], 1);
    __syncthreads();
    for (int i = threadIdx.x; i < nbuk; i += 256) {
        int c = lh[i];
        lbase[i] = c ? atomicAdd(&gcur[i], c) : 0;
        lh[i] = 0;
    }
    __syncthreads();
    for (int e = start + threadIdx.x; e < end; e += 256) {
        int s = src[e];
        int d = dst[e];
        int bk = d >> BUKBITS;
        int r = atomicAdd(&lh[bk], 1);
        tmp[lbase[bk] + r] = ((uint)(d & (BUKSZ - 1)) << 25) | (uint)s;
    }
}

// bucket-local: per-node count, LDS scan -> rowptr+dinv, place eord
__global__ __launch_bounds__(256) void k_fillC(const uint* __restrict__ tmp, const int* __restrict__ bukbase,
                                               int* __restrict__ eord, int* __restrict__ rowptr,
                                               float* __restrict__ dinv, int n, int nbuk) {
    __shared__ int cnt[BUKSZ];
    __shared__ int sc[BUKSZ];
    __shared__ int lrp[BUKSZ];
    int b = blockIdx.x;
    int node0 = b << BUKBITS;
    int nn = min(BUKSZ, n - node0);
    int e0 = bukbase[b], e1 = bukbase[b + 1];
    int t = threadIdx.x;
    if (t < BUKSZ) cnt[t] = 0;
    __syncthreads();
    for (int e = e0 + t; e < e1; e += 256)
        atomicAdd(&cnt[tmp[e] >> 25], 1);
    __syncthreads();
    int c0 = (t < BUKSZ) ? cnt[t] : 0;
    if (t < BUKSZ) sc[t] = c0;
    __syncthreads();
    for (int off = 1; off < BUKSZ; off <<= 1) {
        int v = (t < BUKSZ && t >= off) ? sc[t - off] : 0;
        __syncthreads();
        if (t < BUKSZ) sc[t] += v;
        __syncthreads();
    }
    if (t < BUKSZ) lrp[t] = e0 + sc[t] - c0;
    if (t < nn) {
        rowptr[node0 + t] = e0 + sc[t] - c0;
        dinv[node0 + t] = 1.0f / sqrtf((float)(c0 + 1));  // +1 self-loop
    }
    if (b == nbuk - 1 && t == 0) rowptr[n] = e1;
    __syncthreads();
    if (t < BUKSZ) cnt[t] = 0;
    __syncthreads();
    for (int e = e0 + t; e < e1; e += 256) {
        uint u = tmp[e];
        int dL = (int)(u >> 25);
        int s = (int)(u & 0x1FFFFFFu);
        int r = atomicAdd(&cnt[dL], 1);
        eord[lrp[dL] + r] = s;
    }
}

// ---------------- init: zero-row n in both H buffers (all slices), eord pad = n ----------------
__global__ __launch_bounds__(256) void k_init(ushort* __restrict__ hbuf, ushort* __restrict__ act,
                                              int* __restrict__ eord, int n, int E) {
    int t = threadIdx.x;
    int nr = n + 1;
    if (t < 128) {                       // 8 slices * 16 ushorts
        int s = t >> 4, j = t & 15;
        hbuf[((size_t)s * nr + n) * 16 + j] = 0;
    } else {
        int tt = t - 128;
        int s = tt >> 4, j = tt & 15;
        act[((size_t)s * nr + n) * 16 + j] = 0;
    }
    if (t < 16) eord[E + t] = n;         // pad: dead slots gather the zero row
}

// ---------------- W prep: transpose + bf16 (Wt[n][k]) ----------------
__global__ __launch_bounds__(256) void k_prepW(const float* __restrict__ W1, const float* __restrict__ W2,
                                               ushort* __restrict__ Wt1, ushort* __restrict__ Wt2) {
    int i = blockIdx.x * 256 + threadIdx.x;
    if (i < 16384) {
        int kk = i >> 7, nn = i & 127;
        Wt1[nn * 128 + kk] = f2b(W1[i]);
        Wt2[nn * 128 + kk] = f2b(W2[i]);
    }
}

// ---------------- MFMA GEMM: H[slice][row][m] = bf16(dinv[row] * (X[row] @ W)) ----------------
// A fp32 row-major (layer1) or bf16 SLICE-MAJOR (layer2), slice stride = nr rows.
// MFMA layouts (verified): A[m=lane&15][k=quad*8+j]; B[k][n=lane&15];
// D col=lane&15, row=quad*4+r.  Output dim = t*16+m -> slice=t, within=m.
template <bool ABF16>
__global__ __launch_bounds__(256) void k_gemm(const void* __restrict__ Xv, const ushort* __restrict__ Wt,
                                              const float* __restrict__ dinv, ushort* __restrict__ Hb,
                                              int nrows, int nr) {
    const int wave = threadIdx.x >> 6;
    const int lane = threadIdx.x & 63;
    const int quad = lane >> 4;
    const int m = lane & 15;
    const int row0 = blockIdx.x * 64 + wave * 16;
    const int rowc = min(row0 + m, nrows - 1);

    f32x4 acc[8];
    #pragma unroll
    for (int t = 0; t < 8; t++) acc[t] = (f32x4){0.f, 0.f, 0.f, 0.f};

    #pragma unroll
    for (int ks = 0; ks < 4; ks++) {
        const int k0 = ks * 32 + quad * 8;
        short8 a;
        if (ABF16) {
            // slice-major: slice = k0>>4, within-slice offset = k0&15 (8-aligned, fits in slice)
            const ushort* p = (const ushort*)Xv + (size_t)(k0 >> 4) * nr * 16
                              + (size_t)rowc * 16 + (k0 & 15);
            a = *(const short8*)p;
        } else {
            const float* p = (const float*)Xv + (size_t)rowc * D + k0;
            float4 u0 = ((const float4*)p)[0];
            float4 u1 = ((const float4*)p)[1];
            a[0] = (short)f2b(u0.x); a[1] = (short)f2b(u0.y);
            a[2] = (short)f2b(u0.z); a[3] = (short)f2b(u0.w);
            a[4] = (short)f2b(u1.x); a[5] = (short)f2b(u1.y);
            a[6] = (short)f2b(u1.z); a[7] = (short)f2b(u1.w);
        }
        #pragma unroll
        for (int t = 0; t < 8; t++) {
            short8 b = *(const short8*)(Wt + ((t * 16 + m) * D + k0));
            acc[t] = __builtin_amdgcn_mfma_f32_16x16x32_bf16(a, b, acc[t], 0, 0, 0);
        }
    }
    #pragma unroll
    for (int r = 0; r < 4; r++) {
        int orow = row0 + quad * 4 + r;
        if (orow < nrows) {
            float dvv = dinv[orow];
            #pragma unroll
            for (int t = 0; t < 8; t++)
                Hb[(size_t)t * nr * 16 + (size_t)orow * 16 + m] = f2b(acc[t][r] * dvv);
        }
    }
}

// ---------------- XCD-sliced CSR aggregation (slice-major H, 4 nodes/wave) ----------------
// Block b -> slice b%8 (-> XCD b%8). Wave: 4 consecutive nodes x 16 edge-slots
// per iteration. Dead slots resolve to eord pad -> zero row n (no masking).
// 32-bit slice-local gather addressing (slice = 3.2 MB). Manual 2-stage
// pipeline: next iteration's 8 index loads issued before current gathers are
// consumed -> 16 loads in flight per wave.
template <bool RELU, bool OBF16>
__global__ __launch_bounds__(256, 8) void k_agg_slice(const ushort* __restrict__ Hb,
                                                      const float* __restrict__ dinv,
                                                      const int* __restrict__ rowptr,
                                                      const int* __restrict__ eord,
                                                      const float* __restrict__ bias,
                                                      void* __restrict__ outp, int n, int E) {
    const int slice = blockIdx.x & (NSLICE - 1);
    const int blk = blockIdx.x >> 3;                      // block index within slice
    const int wid = (blk << 2) + (threadIdx.x >> 6);      // wave index within slice [0,1024)
    const int lane = threadIdx.x & 63;
    const int g = lane >> 3;                              // edge subgroup 0..7
    const int w = lane & 7;                               // dword within slice 0..7
    const int cofs = slice * 8 + w;                       // dword offset within 64-dword row
    const int nr = n + 1;                                 // rows per slice (row n = zeros)
    const size_t sb = (size_t)slice * nr * 8;             // dword base of this slice
    const uint* __restrict__ Hs = (const uint*)Hb + sb;   // slice-local base (SGPR)
    const int epad = E + g;                               // pad entries contain n
    const float2 bb = ((const float2*)bias)[cofs];

    for (int v0 = wid * 4; v0 < n; v0 += WAVES_PER_SLICE * 4) {
        int rp0 = rowptr[v0];
        int rp1 = rowptr[min(v0 + 1, n)];
        int rp2 = rowptr[min(v0 + 2, n)];
        int rp3 = rowptr[min(v0 + 3, n)];
        int rp4 = rowptr[min(v0 + 4, n)];
        int d0 = rp1 - rp0, d1 = rp2 - rp1, d2 = rp3 - rp2, d3 = rp4 - rp3;
        int maxd = max(max(d0, d1), max(d2, d3));

        f32x2 a0 = {0.f, 0.f}, a1 = {0.f, 0.f}, a2 = {0.f, 0.f}, a3 = {0.f, 0.f};

#define LOADIDX(arr, KK) {                                        \
            int oA = (KK) + g, oB = oA + 8;                       \
            arr[0] = eord[(oA < d0) ? (rp0 + oA) : epad];         \
            arr[1] = eord[(oB < d0) ? (rp0 + oB) : epad];         \
            arr[2] = eord[(oA < d1) ? (rp1 + oA) : epad];         \
            arr[3] = eord[(oB < d1) ? (rp1 + oB) : epad];         \
            arr[4] = eord[(oA < d2) ? (rp2 + oA) : epad];         \
            arr[5] = eord[(oB < d2) ? (rp2 + oB) : epad];         \
            arr[6] = eord[(oA < d3) ? (rp3 + oA) : epad];         \
            arr[7] = eord[(oB < d3) ? (rp3 + oB) : epad]; }

        if (maxd > 0) {
            int ia[8];
            LOADIDX(ia, 0)
            for (int k = 0;; k += 16) {
                uint h[8];
                #pragma unroll
                for (int i = 0; i < 8; i++)
                    h[i] = Hs[((uint)ia[i] << 3) + (uint)w];      // 32-bit offset, SGPR base
                const bool more = (k + 16 < maxd);                // wave-uniform branch
                int ib[8];
                if (more) { LOADIDX(ib, k + 16) }                 // in flight over gather use
                #pragma unroll
                for (int i = 0; i < 8; i++) {
                    f32x2 t = { __uint_as_float(h[i] << 16),
                                __uint_as_float(h[i] & 0xffff0000u) };
                    if (i < 2) a0 += t; else if (i < 4) a1 += t;
                    else if (i < 6) a2 += t; else a3 += t;
                }
                if (!more) break;
                #pragma unroll
                for (int i = 0; i < 8; i++) ia[i] = ib[i];
            }
        }
#undef LOADIDX

        // butterfly over the 8 edge-groups (lanes with equal w)
        a0.x += __shfl_xor(a0.x, 8);  a0.y += __shfl_xor(a0.y, 8);
        a1.x += __shfl_xor(a1.x, 8);  a1.y += __shfl_xor(a1.y, 8);
        a2.x += __shfl_xor(a2.x, 8);  a2.y += __shfl_xor(a2.y, 8);
        a3.x += __shfl_xor(a3.x, 8);  a3.y += __shfl_xor(a3.y, 8);
        a0.x += __shfl_xor(a0.x, 16); a0.y += __shfl_xor(a0.y, 16);
        a1.x += __shfl_xor(a1.x, 16); a1.y += __shfl_xor(a1.y, 16);
        a2.x += __shfl_xor(a2.x, 16); a2.y += __shfl_xor(a2.y, 16);
        a3.x += __shfl_xor(a3.x, 16); a3.y += __shfl_xor(a3.y, 16);
        a0.x += __shfl_xor(a0.x, 32); a0.y += __shfl_xor(a0.y, 32);
        a1.x += __shfl_xor(a1.x, 32); a1.y += __shfl_xor(a1.y, 32);
        a2.x += __shfl_xor(a2.x, 32); a2.y += __shfl_xor(a2.y, 32);
        a3.x += __shfl_xor(a3.x, 32); a3.y += __shfl_xor(a3.y, 32);

        // group i (lanes 8i..8i+7, i<4) writes node v0+i
        const int i = g;
        if (i < 4) {
            int v = v0 + i;
            if (v < n) {
                float axv = (i == 0) ? a0.x : (i == 1) ? a1.x : (i == 2) ? a2.x : a3.x;
                float ayv = (i == 0) ? a0.y : (i == 1) ? a1.y : (i == 2) ? a2.y : a3.y;
                uint hs = Hs[((uint)v << 3) + (uint)w];   // self-loop term (resident slice)
                float dv = dinv[v];
                float rx = dv * (axv + __uint_as_float(hs << 16)) + bb.x;
                float ry = dv * (ayv + __uint_as_float(hs & 0xffff0000u)) + bb.y;
                if (RELU) { rx = fmaxf(rx, 0.f); ry = fmaxf(ry, 0.f); }
                if (OBF16) {
                    uint wd = ((uint)f2b(ry) << 16) | (uint)f2b(rx);
                    __builtin_nontemporal_store(wd, (uint*)outp + sb + ((uint)v << 3) + (uint)w);
                } else {
                    f32x2 r2 = {rx, ry};
                    __builtin_nontemporal_store(r2, (f32x2*)outp + (size_t)v * 64 + cofs);
                }
            }
        }
    }
}

// ---------------- launcher ----------------

static inline size_t alignup(size_t x) { return (x + 511) & ~(size_t)511; }

extern "C" void kernel_launch(void* const* d_in, const int* in_sizes, int n_in,
                              void* d_out, int out_size, void* d_ws, size_t ws_size,
                              hipStream_t stream) {
    const float* x  = (const float*)d_in[0];
    const int* eidx = (const int*)d_in[1];   // [2,E]: src row, dst row (int32)
    const float* W1 = (const float*)d_in[2];
    const float* b1 = (const float*)d_in[3];
    const float* W2 = (const float*)d_in[4];
    const float* b2 = (const float*)d_in[5];
    float* out = (float*)d_out;

    const int N = in_sizes[0] / D;
    const int E = in_sizes[1] / 2;
    const int NR = N + 1;                     // rows per slice incl. zero row
    const int* src = eidx;
    const int* dst = eidx + E;
    const int nbuk = (N + BUKSZ - 1) >> BUKBITS;   // 782

    // workspace
    char* ws = (char*)d_ws;
    size_t off = 0;
    int* bukcnt = (int*)(ws + off);   off = alignup(off + (size_t)MAXBUK * 4);
    int* bukbase = (int*)(ws + off);  off = alignup(off + (size_t)(MAXBUK + 1) * 4);
    int* gcur   = (int*)(ws + off);   off = alignup(off + (size_t)MAXBUK * 4);
    int* rowptr = (int*)(ws + off);   off = alignup(off + (size_t)(N + 1) * 4);
    float* dinv = (float*)(ws + off); off = alignup(off + (size_t)N * 4);
    int* eord   = (int*)(ws + off);   off = alignup(off + (size_t)(E + 16) * 4);
    ushort* hbuf = (ushort*)(ws + off); off = alignup(off + (size_t)NR * D * 2);
    ushort* act  = (ushort*)(ws + off); off = alignup(off + (size_t)NR * D * 2);
    ushort* Wt1 = (ushort*)(ws + off); off = alignup(off + 16384 * 2);
    ushort* Wt2 = (ushort*)(ws + off); off = alignup(off + 16384 * 2);
    uint* tmp = (uint*)hbuf;  // E uints (6.4 MB) alias hbuf; dead before k_init/gemm1 writes
    (void)ws_size;

    const int nT = 256;
    const int gChunk = (E + SCHUNK - 1) / SCHUNK;   // 98

    hipMemsetAsync(bukcnt, 0, (size_t)MAXBUK * 4, stream);
    k_prepW<<<64, nT, 0, stream>>>(W1, W2, Wt1, Wt2);
    k_bukhist<<<gChunk, nT, 0, stream>>>(dst, bukcnt, E, nbuk);
    k_bukscan<<<1, nT, 0, stream>>>(bukcnt, bukbase, gcur, nbuk, E);
    k_scatter<<<gChunk, nT, 0, stream>>>(src, dst, gcur, tmp, E, nbuk);
    k_fillC<<<nbuk, nT, 0, stream>>>(tmp, bukbase, eord, rowptr, dinv, N, nbuk);
    k_init<<<1, nT, 0, stream>>>(hbuf, act, eord, N, E);   // after fillC: tmp (alias) dead

    const int gGemm = (N + 63) / 64;

    // layer 1: hbuf = bf16(dinv*(x @ W1)) slice-major; act(bf16 slice-major) = relu(agg + b1)
    k_gemm<false><<<gGemm, nT, 0, stream>>>((const void*)x, Wt1, dinv, hbuf, N, NR);
    k_agg_slice<true, true><<<AGG_BLOCKS, nT, 0, stream>>>(hbuf, dinv, rowptr, eord, b1, (void*)act, N, E);

    // layer 2: hbuf = bf16(dinv*(act @ W2)) slice-major; out(fp32 row-major) = agg + b2
    k_gemm<true><<<gGemm, nT, 0, stream>>>((const void*)act, Wt2, dinv, hbuf, N, NR);
    k_agg_slice<false, false><<<AGG_BLOCKS, nT, 0, stream>>>(hbuf, dinv, rowptr, eord, b2, (void*)out, N, E);
}